// Round 11
// baseline (1528.418 us; speedup 1.0000x reference)
//
#include <hip/hip_runtime.h>
#include <hip/hip_bf16.h>
#include <math.h>

typedef unsigned short u16;
typedef unsigned long long u64;
using bf16x8 = __attribute__((ext_vector_type(8))) short;
using f32x4  = __attribute__((ext_vector_type(4))) float;

static constexpr int kD = 768;
static constexpr int kH = 12;
static constexpr int kL = 6;
static constexpr int kF = 3072;
static constexpr int kS = 2048;
static constexpr int kB = 4;
static constexpr int kQW = 2304;          // fused QKV width
static constexpr int kNT = kB * kS;       // 8192 tokens

// Q prescale: 1/sqrt(64) * log2(e)  -> scores come out in log2 units
static constexpr float kQScale = 0.18033688011112043f;

__device__ __forceinline__ u16 f2bf(float f) {
    return __bfloat16_as_ushort(__float2bfloat16(f));
}
__device__ __forceinline__ float b2f(u16 u) {
    return __uint_as_float((unsigned)u << 16);
}
__device__ __forceinline__ unsigned cvtpk(float a, float b) {
    unsigned d;
    asm volatile("v_cvt_pk_bf16_f32 %0, %1, %2" : "=v"(d) : "v"(a), "v"(b));
    return d;
}
__device__ __forceinline__ float exp2fast(float x) {
#if __has_builtin(__builtin_amdgcn_exp2f)
    return __builtin_amdgcn_exp2f(x);
#else
    return __expf(x * 0.6931471805599453f);
#endif
}

__device__ __forceinline__ void gload16(const void* g, void* l) {
    auto gp = reinterpret_cast<const __attribute__((address_space(1))) unsigned int*>(
        reinterpret_cast<uintptr_t>(g));
    auto lp = reinterpret_cast<__attribute__((address_space(3))) unsigned int*>(
        reinterpret_cast<uintptr_t>(l));
    __builtin_amdgcn_global_load_lds(gp, lp, 16, 0, 0);
}

// ---------------------------------------------------------------------------
// Embedding + sinusoidal PE -> bf16 residual stream
// ---------------------------------------------------------------------------
__global__ __launch_bounds__(256) void embed_pe(
    const int* __restrict__ ids, const float* __restrict__ emb,
    u16* __restrict__ xbf)
{
    const int t = blockIdx.x;
    const int s = t & (kS - 1);
    const int id = ids[t];
#pragma unroll
    for (int j = 0; j < 3; ++j) {
        const int d = threadIdx.x + (j << 8);
        const float i2 = (float)((d >> 1) << 1);
        const float dv = __expf(i2 * (-9.210340371976184f / 768.f));
        const float ang = (float)s * dv;
        const float pe = (d & 1) ? cosf(ang) : sinf(ang);
        xbf[(size_t)t * kD + d] = f2bf(emb[(size_t)id * kD + d] + pe);
    }
}

__global__ __launch_bounds__(256) void embed_pe_f32(
    const int* __restrict__ ids, const float* __restrict__ emb,
    float* __restrict__ x)
{
    const int t = blockIdx.x;
    const int s = t & (kS - 1);
    const int id = ids[t];
#pragma unroll
    for (int j = 0; j < 3; ++j) {
        const int d = threadIdx.x + (j << 8);
        const float i2 = (float)((d >> 1) << 1);
        const float dv = __expf(i2 * (-9.210340371976184f / 768.f));
        const float ang = (float)s * dv;
        const float pe = (d & 1) ? cosf(ang) : sinf(ang);
        x[(size_t)t * kD + d] = emb[(size_t)id * kD + d] + pe;
    }
}

// mask bitmask: bit k of word (b*32+kt) = (ids[b*2048+kt*64+k] != 1)
__global__ __launch_bounds__(64) void mk_maskbits(const int* __restrict__ ids,
                                                  u64* __restrict__ mbits)
{
    const int w = blockIdx.x;
    const int lane = threadIdx.x;
    const u64 m = __ballot(ids[(size_t)w * 64 + lane] != 1);
    if (lane == 0) mbits[w] = m;
}

// bias arena: per layer 6912 floats: [qkv(bq*kQScale|bk|bv) | bo | b1 | b2]
__global__ __launch_bounds__(256) void bias_build(
    const float* __restrict__ bq, const float* __restrict__ bk,
    const float* __restrict__ bv, const float* __restrict__ bo,
    const float* __restrict__ b1, const float* __restrict__ b2,
    float* __restrict__ ba)
{
    const int i = blockIdx.x * 256 + threadIdx.x;
    if (i >= 6 * 6912) return;
    const int l = i / 6912, p = i % 6912;
    float v;
    if      (p < 768)  v = bq[l * 768 + p] * kQScale;
    else if (p < 1536) v = bk[l * 768 + p - 768];
    else if (p < 2304) v = bv[l * 768 + p - 1536];
    else if (p < 3072) v = bo[l * 768 + p - 2304];
    else if (p < 6144) v = b1[(size_t)l * 3072 + p - 3072];
    else               v = b2[l * 768 + p - 6144];
    ba[i] = v;
}

// ---------------------------------------------------------------------------
// Per-layer weight converter: all 6 matrices -> transposed bf16 arena.
// ---------------------------------------------------------------------------
static constexpr size_t OFF_WO = (size_t)2304 * 768;
static constexpr size_t OFF_W1 = OFF_WO + (size_t)768 * 768;
static constexpr size_t OFF_W2 = OFF_W1 + (size_t)3072 * 768;
static constexpr size_t WARENA_E = OFF_W2 + (size_t)768 * 3072;

__global__ __launch_bounds__(256) void cvt_all(
    const float* __restrict__ Wq, const float* __restrict__ Wk,
    const float* __restrict__ Wv, const float* __restrict__ Wo,
    const float* __restrict__ W1, const float* __restrict__ W2,
    u16* __restrict__ wa)
{
    __shared__ float T[64][68];
    const int t = blockIdx.x;
    const float* S; u16* Dp; int Nsrc, Kdst, srow0, scol0; float sc = 1.f;
    if (t < 432) {
        const int ni = t % 36, ki = t / 36;
        const int ng = ni * 64;
        const int sel = ng / 768;
        scol0 = ng % 768; srow0 = ki * 64;
        S = (sel == 0) ? Wq : (sel == 1) ? Wk : Wv;
        if (sel == 0) sc = kQScale;
        Nsrc = 768; Kdst = 768;
        Dp = wa + (size_t)ng * 768 + srow0;
    } else if (t < 576) {
        const int tt = t - 432; const int ni = tt % 12, ki = tt / 12;
        scol0 = ni * 64; srow0 = ki * 64;
        S = Wo; Nsrc = 768; Kdst = 768;
        Dp = wa + OFF_WO + (size_t)(ni * 64) * 768 + srow0;
    } else if (t < 1152) {
        const int tt = t - 576; const int ni = tt % 48, ki = tt / 48;
        scol0 = ni * 64; srow0 = ki * 64;
        S = W1; Nsrc = 3072; Kdst = 768;
        Dp = wa + OFF_W1 + (size_t)(ni * 64) * 768 + srow0;
    } else {
        const int tt = t - 1152; const int ni = tt % 12, ki = tt / 12;
        scol0 = ni * 64; srow0 = ki * 64;
        S = W2; Nsrc = 768; Kdst = 3072;
        Dp = wa + OFF_W2 + (size_t)(ni * 64) * 3072 + srow0;
    }
    const int tid = threadIdx.x;
#pragma unroll
    for (int i = 0; i < 4; ++i) {
        const int idx = tid + (i << 8);
        const int kr = idx >> 4;
        const int nc = (idx & 15) << 2;
        const float4 v = *(const float4*)(S + (size_t)(srow0 + kr) * Nsrc + scol0 + nc);
        T[kr][nc] = v.x; T[kr][nc + 1] = v.y; T[kr][nc + 2] = v.z; T[kr][nc + 3] = v.w;
    }
    __syncthreads();
#pragma unroll
    for (int i = 0; i < 4; ++i) {
        const int idx = tid + (i << 8);
        const int nr = idx >> 4;
        const int kc = (idx & 15) << 2;
        ushort4 o;
        o.x = f2bf(T[kc][nr] * sc);     o.y = f2bf(T[kc + 1][nr] * sc);
        o.z = f2bf(T[kc + 2][nr] * sc); o.w = f2bf(T[kc + 3][nr] * sc);
        *(ushort4*)(Dp + (size_t)nr * Kdst + kc) = o;
    }
}

// ---------------------------------------------------------------------------
// gemm256b: 128x256 tile, BK=32, 4 waves, TRIPLE-buffered LDS (72KB),
// counted vmcnt(6), single barrier per K-step, 2 blocks/CU.
// mode: 1=bf16 out, 2=bf16+ReLU, 3=QKV (cols>=1536 -> permuted vT)
// ---------------------------------------------------------------------------
__global__ __launch_bounds__(256, 2) void gemm256b(
    const u16* __restrict__ A, const u16* __restrict__ Bt,
    const float* __restrict__ bias, void* __restrict__ Cv,
    u16* __restrict__ vTp, int M, int N, int K, int mode)
{
    __shared__ u16 As[3][4096];      // 128 rows x 32 K
    __shared__ u16 Bs[3][8192];      // 256 cols x 32 K
    const int tid = threadIdx.x;
    const int l = tid & 63;
    const int lo = l & 15, hi = l >> 4;
    const int wc = tid >> 6;         // 4 waves: 1 (M) x 4 (N)

    int brow = blockIdx.x, bcol = blockIdx.y;
    const int gx = gridDim.x;
    if ((gx & 7) == 0) {
        const int id = blockIdx.y * gx + blockIdx.x;
        const int xcd = id & 7, idx = id >> 3;
        const int rpx = gx >> 3;
        brow = xcd * rpx + (idx % rpx);
        bcol = idx / rpx;
    }
    const size_t row0 = (size_t)brow * 128;
    const size_t col0 = (size_t)bcol * 256;

    const int ca0 = tid, ca1 = tid + 256;
    const int ra0 = ca0 >> 2, ga0 = (ca0 & 3) ^ ((ra0 >> 1) & 3);
    const int ra1 = ca1 >> 2, ga1 = (ca1 & 3) ^ ((ra1 >> 1) & 3);
    const u16* aP0 = A + (row0 + ra0) * K + ga0 * 8;
    const u16* aP1 = A + (row0 + ra1) * K + ga1 * 8;
    const u16* bP[4];
#pragma unroll
    for (int q = 0; q < 4; ++q) {
        const int c = tid + (q << 8);
        const int r = c >> 2, g = (c & 3) ^ ((r >> 1) & 3);
        bP[q] = Bt + (col0 + r) * K + g * 8;
    }

    f32x4 acc[8][4];
#pragma unroll
    for (int i = 0; i < 8; ++i)
#pragma unroll
        for (int j = 0; j < 4; ++j)
#pragma unroll
            for (int r = 0; r < 4; ++r) acc[i][j][r] = 0.f;

    int aoff[8], boff[4];
#pragma unroll
    for (int i = 0; i < 8; ++i) {
        const int ra = i * 16 + lo;
        aoff[i] = ra * 32 + ((hi ^ ((ra >> 1) & 3)) << 3);
    }
#pragma unroll
    for (int j = 0; j < 4; ++j) {
        const int rb = wc * 64 + j * 16 + lo;
        boff[j] = rb * 32 + ((hi ^ ((rb >> 1) & 3)) << 3);
    }

    const int NT = K >> 5;
    // prologue: stage K-steps 0 and 1
#pragma unroll
    for (int t = 0; t < 2; ++t) {
        const int k0 = t << 5;
        gload16(aP0 + k0, As[t] + ca0 * 8);
        gload16(aP1 + k0, As[t] + ca1 * 8);
#pragma unroll
        for (int q = 0; q < 4; ++q)
            gload16(bP[q] + k0, Bs[t] + (tid + (q << 8)) * 8);
    }

    int cur = 0;
    for (int t = 0; t < NT; ++t) {
        if (t + 1 < NT) {
            asm volatile("s_waitcnt vmcnt(6)" ::: "memory");  // step t landed
        } else {
            asm volatile("s_waitcnt vmcnt(0)" ::: "memory");
        }
        __builtin_amdgcn_s_barrier();
        if (t + 2 < NT) {
            const int k0 = (t + 2) << 5;
            const int nb = (cur + 2 >= 3) ? cur - 1 : cur + 2;
            gload16(aP0 + k0, As[nb] + ca0 * 8);
            gload16(aP1 + k0, As[nb] + ca1 * 8);
#pragma unroll
            for (int q = 0; q < 4; ++q)
                gload16(bP[q] + k0, Bs[nb] + (tid + (q << 8)) * 8);
        }
        bf16x8 af[8], bfr[4];
#pragma unroll
        for (int i = 0; i < 8; ++i) af[i]  = *(const bf16x8*)&As[cur][aoff[i]];
#pragma unroll
        for (int j = 0; j < 4; ++j) bfr[j] = *(const bf16x8*)&Bs[cur][boff[j]];
        __builtin_amdgcn_s_setprio(1);
#pragma unroll
        for (int i = 0; i < 8; ++i)
#pragma unroll
            for (int j = 0; j < 4; ++j)
                acc[i][j] = __builtin_amdgcn_mfma_f32_16x16x32_bf16(
                    af[i], bfr[j], acc[i][j], 0, 0, 0);
        __builtin_amdgcn_s_setprio(0);
        cur = (cur + 1 == 3) ? 0 : cur + 1;
    }

    const bool vmode = (mode == 3) && (col0 >= 1536);
    if (vmode) {
#pragma unroll
        for (int i = 0; i < 8; ++i) {
            const size_t rbase = row0 + i * 16 + hi * 4;     // token, %4==0
            const size_t tb = (rbase >> 6) * 64;
            const int k0 = (int)(rbase & 63);
            const int pos = (((k0 >> 2) & 3) << 3) + (((k0 >> 4) & 1) << 2)
                          + ((k0 >> 5) << 5);
#pragma unroll
            for (int j = 0; j < 4; ++j) {
                const size_t c = col0 + wc * 64 + j * 16 + lo;
                const float bs = bias[c];
                const size_t d = c - 1536;
                ushort4 o;
                o.x = f2bf(acc[i][j][0] + bs);
                o.y = f2bf(acc[i][j][1] + bs);
                o.z = f2bf(acc[i][j][2] + bs);
                o.w = f2bf(acc[i][j][3] + bs);
                *(ushort4*)(vTp + d * (size_t)M + tb + pos) = o;
            }
        }
        return;
    }

#pragma unroll
    for (int i = 0; i < 8; ++i) {
        const size_t rbase = row0 + i * 16 + hi * 4;
#pragma unroll
        for (int j = 0; j < 4; ++j) {
            const size_t c = col0 + wc * 64 + j * 16 + lo;
            const float bs = bias[c];
#pragma unroll
            for (int r = 0; r < 4; ++r) {
                float v = acc[i][j][r] + bs;
                if (mode == 2) v = fmaxf(v, 0.f);
                ((u16*)Cv)[(rbase + r) * (size_t)N + c] = f2bf(v);
            }
        }
    }
}

// ---------------------------------------------------------------------------
// gemm_bf16: 128x128 tile (WO / FFN2), TRIPLE-buffered (48KB LDS),
// counted vmcnt(4), single barrier per K-step.
// ---------------------------------------------------------------------------
__global__ __launch_bounds__(256) void gemm_bf16(
    const u16* __restrict__ A, const u16* __restrict__ Bt,
    const float* __restrict__ bias, void* __restrict__ Cv,
    u16* __restrict__ vTp, int M, int N, int K, int mode)
{
    __shared__ u16 As[3][4096];
    __shared__ u16 Bs[3][4096];
    const int tid = threadIdx.x;
    const int l = tid & 63;
    const int lo = l & 15, hi = l >> 4;
    const int w = tid >> 6, wr = w >> 1, wc = w & 1;

    int brow = blockIdx.x, bcol = blockIdx.y;
    const int gx = gridDim.x;
    if ((gx & 7) == 0) {
        const int id = blockIdx.y * gx + blockIdx.x;
        const int xcd = id & 7, idx = id >> 3;
        const int rpx = gx >> 3;
        brow = xcd * rpx + (idx % rpx);
        bcol = idx / rpx;
    }
    const size_t row0 = (size_t)brow * 128;
    const size_t col0 = (size_t)bcol * 128;

    const int c0 = tid, c1 = tid + 256;
    const int r0 = c0 >> 2, g0 = (c0 & 3) ^ ((r0 >> 1) & 3);
    const int r1 = c1 >> 2, g1 = (c1 & 3) ^ ((r1 >> 1) & 3);
    const u16* a0 = A  + (row0 + r0) * K + g0 * 8;
    const u16* a1 = A  + (row0 + r1) * K + g1 * 8;
    const u16* b0 = Bt + (col0 + r0) * K + g0 * 8;
    const u16* b1 = Bt + (col0 + r1) * K + g1 * 8;

    f32x4 acc[4][4];
#pragma unroll
    for (int i = 0; i < 4; ++i)
#pragma unroll
        for (int j = 0; j < 4; ++j)
#pragma unroll
            for (int r = 0; r < 4; ++r) acc[i][j][r] = 0.f;

    int aoff[4], boff[4];
#pragma unroll
    for (int i = 0; i < 4; ++i) {
        const int ra = wr * 64 + i * 16 + lo;
        aoff[i] = ra * 32 + ((hi ^ ((ra >> 1) & 3)) << 3);
        const int rb = wc * 64 + i * 16 + lo;
        boff[i] = rb * 32 + ((hi ^ ((rb >> 1) & 3)) << 3);
    }

    const int NT = K >> 5;
    // prologue: stage K-steps 0 and 1
#pragma unroll
    for (int t = 0; t < 2; ++t) {
        const int k0 = t << 5;
        gload16(a0 + k0, As[t] + c0 * 8);
        gload16(a1 + k0, As[t] + c1 * 8);
        gload16(b0 + k0, Bs[t] + c0 * 8);
        gload16(b1 + k0, Bs[t] + c1 * 8);
    }

    int cur = 0;
    for (int t = 0; t < NT; ++t) {
        if (t + 1 < NT) {
            asm volatile("s_waitcnt vmcnt(4)" ::: "memory");  // step t landed
        } else {
            asm volatile("s_waitcnt vmcnt(0)" ::: "memory");
        }
        __builtin_amdgcn_s_barrier();
        if (t + 2 < NT) {
            const int k0 = (t + 2) << 5;
            const int nb = (cur + 2 >= 3) ? cur - 1 : cur + 2;
            gload16(a0 + k0, As[nb] + c0 * 8);
            gload16(a1 + k0, As[nb] + c1 * 8);
            gload16(b0 + k0, Bs[nb] + c0 * 8);
            gload16(b1 + k0, Bs[nb] + c1 * 8);
        }
        bf16x8 af[4], bfr[4];
#pragma unroll
        for (int i = 0; i < 4; ++i) af[i]  = *(const bf16x8*)&As[cur][aoff[i]];
#pragma unroll
        for (int j = 0; j < 4; ++j) bfr[j] = *(const bf16x8*)&Bs[cur][boff[j]];
        __builtin_amdgcn_s_setprio(1);
#pragma unroll
        for (int i = 0; i < 4; ++i)
#pragma unroll
            for (int j = 0; j < 4; ++j)
                acc[i][j] = __builtin_amdgcn_mfma_f32_16x16x32_bf16(
                    af[i], bfr[j], acc[i][j], 0, 0, 0);
        __builtin_amdgcn_s_setprio(0);
        cur = (cur + 1 == 3) ? 0 : cur + 1;
    }

#pragma unroll
    for (int i = 0; i < 4; ++i) {
        const size_t rbase = row0 + wr * 64 + i * 16 + hi * 4;
#pragma unroll
        for (int j = 0; j < 4; ++j) {
            const size_t c = col0 + wc * 64 + j * 16 + lo;
            const float bs = bias[c];
#pragma unroll
            for (int r = 0; r < 4; ++r) {
                float v = acc[i][j][r] + bs;
                if (mode == 2) v = fmaxf(v, 0.f);
                ((u16*)Cv)[(rbase + r) * (size_t)N + c] = f2bf(v);
            }
        }
    }
}

// ---------------------------------------------------------------------------
// MFMA flash attention v8 — triple-buffered K/V, counted vmcnt(2)
// (loads stay in flight across the barrier), 128 q-rows/block, XCD swizzle.
// Grid (S/128, H, B) flat-swizzled; 512 threads.
// ---------------------------------------------------------------------------
__global__ __launch_bounds__(512) void attn_mfma(
    const u16* __restrict__ QKV, const u16* __restrict__ vT,
    const u64* __restrict__ mbits, u16* __restrict__ O)
{
    __shared__ u16 Ks[3][4096];   // [key][64 d], slot-swizzled
    __shared__ u16 Vs[3][4096];   // [d][64 pos], slot-swizzled

    const int tid = threadIdx.x, l = tid & 63, w = tid >> 6;
    const int lo = l & 15, hi = l >> 4;

    const int flat = blockIdx.x + 16 * (blockIdx.y + 12 * blockIdx.z);
    const int nf = (flat & 7) * 96 + (flat >> 3);
    const int qi = nf & 15;
    const int h  = (nf >> 4) % 12;
    const int b  = nf / 192;
    const int q0 = qi << 7;

    bf16x8 qf0, qf1;
    {
        const u16* qp = QKV + ((size_t)(b * kS + q0 + w * 16 + lo)) * kQW
                            + h * 64 + hi * 8;
        qf0 = *(const bf16x8*)qp;
        qf1 = *(const bf16x8*)(qp + 32);
    }

    const int rw = tid >> 3, sx = tid & 7, E = sx ^ (rw & 7);
    const u16* Kbase = QKV + (size_t)(b * kS) * kQW + 768 + h * 64;
    const u16* Vbase = vT + (size_t)(h * 64) * kNT + b * kS;

    f32x4 accO[4];
#pragma unroll
    for (int n = 0; n < 4; ++n)
#pragma unroll
        for (int r = 0; r < 4; ++r) accO[n][r] = 0.f;
    float m = -3.0e38f, lsum = 0.f;

    const int ksw = (lo & 7) << 3;
    constexpr int NTt = kS / 64;

    // prologue: stage tiles 0 and 1 (K then V per tile; 4 loads in flight)
#pragma unroll
    for (int t = 0; t < 2; ++t) {
        const size_t kof = (size_t)(t << 6) * kQW;
        const size_t vof = (size_t)(t << 6);
        gload16(Kbase + kof + (size_t)rw * kQW + E * 8, Ks[t] + tid * 8);
        gload16(Vbase + (size_t)rw * kNT + vof + E * 8, Vs[t] + tid * 8);
    }

    int cur = 0;
    for (int kt = 0; kt < NTt; ++kt) {
        if (kt + 1 < NTt) {
            asm volatile("s_waitcnt vmcnt(2)" ::: "memory");  // tile kt landed
        } else {
            asm volatile("s_waitcnt vmcnt(0)" ::: "memory");
        }
        __syncthreads();

        if (kt + 2 < NTt) {
            const size_t kof = (size_t)((kt + 2) << 6) * kQW;
            const size_t vof = (size_t)((kt + 2) << 6);
            const int nb = (cur + 2 >= 3) ? cur - 1 : cur + 2;
            gload16(Kbase + kof + (size_t)rw * kQW + E * 8, Ks[nb] + tid * 8);
            gload16(Vbase + (size_t)rw * kNT + vof + E * 8, Vs[nb] + tid * 8);
        }

        f32x4 st[4];
        __builtin_amdgcn_s_setprio(1);
#pragma unroll
        for (int j = 0; j < 4; ++j) {
#pragma unroll
            for (int r = 0; r < 4; ++r) st[j][r] = 0.f;
            const int kb2 = (j * 16 + lo) * 64;
            const bf16x8 k0 = *(const bf16x8*)&Ks[cur][kb2 + ((hi * 8)      ^ ksw)];
            const bf16x8 k1 = *(const bf16x8*)&Ks[cur][kb2 + ((hi * 8 + 32) ^ ksw)];
            st[j] = __builtin_amdgcn_mfma_f32_16x16x32_bf16(k0, qf0, st[j], 0, 0, 0);
            st[j] = __builtin_amdgcn_mfma_f32_16x16x32_bf16(k1, qf1, st[j], 0, 0, 0);
        }
        __builtin_amdgcn_s_setprio(0);

        float rmax = st[0][0];
#pragma unroll
        for (int j = 0; j < 4; ++j)
#pragma unroll
            for (int r = 0; r < 4; ++r) rmax = fmaxf(rmax, st[j][r]);
        rmax = fmaxf(rmax, __shfl_xor(rmax, 16));
        rmax = fmaxf(rmax, __shfl_xor(rmax, 32));

        const bool skip = __all(rmax <= m + 11.0f);
        if (!skip) {
            const float mn = fmaxf(m, rmax);
            const float corr = exp2fast(m - mn);
            m = mn;
            lsum *= corr;
            float c2[4];
#pragma unroll
            for (int r = 0; r < 4; ++r) c2[r] = __shfl(corr, hi * 4 + r);
#pragma unroll
            for (int n = 0; n < 4; ++n)
#pragma unroll
                for (int r = 0; r < 4; ++r) accO[n][r] *= c2[r];
        }

#pragma unroll
        for (int j = 0; j < 4; ++j)
#pragma unroll
            for (int r = 0; r < 4; ++r) st[j][r] = exp2fast(st[j][r] - m);

        const u64 mb = mbits[b * 32 + kt];
        if (mb != ~0ull) {
#pragma unroll
            for (int j = 0; j < 4; ++j)
#pragma unroll
                for (int r = 0; r < 4; ++r)
                    if (!((mb >> (j * 16 + hi * 4 + r)) & 1)) st[j][r] = 0.f;
        }

        float ts = 0.f;
#pragma unroll
        for (int j = 0; j < 4; ++j)
#pragma unroll
            for (int r = 0; r < 4; ++r) ts += st[j][r];
        ts += __shfl_xor(ts, 16);
        ts += __shfl_xor(ts, 32);
        lsum += ts;

        union PU { unsigned u[4]; bf16x8 v; } p0, p1;
        p0.u[0] = cvtpk(st[0][0], st[0][1]); p0.u[1] = cvtpk(st[0][2], st[0][3]);
        p0.u[2] = cvtpk(st[1][0], st[1][1]); p0.u[3] = cvtpk(st[1][2], st[1][3]);
        p1.u[0] = cvtpk(st[2][0], st[2][1]); p1.u[1] = cvtpk(st[2][2], st[2][3]);
        p1.u[2] = cvtpk(st[3][0], st[3][1]); p1.u[3] = cvtpk(st[3][2], st[3][3]);

        __builtin_amdgcn_s_setprio(1);
#pragma unroll
        for (int n = 0; n < 4; ++n) {
            const int vb2 = (n * 16 + lo) * 64;
            const bf16x8 v0 = *(const bf16x8*)&Vs[cur][vb2 + ((hi * 8)      ^ ksw)];
            const bf16x8 v1 = *(const bf16x8*)&Vs[cur][vb2 + ((hi * 8 + 32) ^ ksw)];
            accO[n] = __builtin_amdgcn_mfma_f32_16x16x32_bf16(p0.v, v0, accO[n], 0, 0, 0);
            accO[n] = __builtin_amdgcn_mfma_f32_16x16x32_bf16(p1.v, v1, accO[n], 0, 0, 0);
        }
        __builtin_amdgcn_s_setprio(0);
        cur = (cur + 1 == 3) ? 0 : cur + 1;
    }

    float linv[4];
#pragma unroll
    for (int r = 0; r < 4; ++r) linv[r] = 1.f / __shfl(lsum, hi * 4 + r);
#pragma unroll
    for (int n = 0; n < 4; ++n)
#pragma unroll
        for (int r = 0; r < 4; ++r)
            O[((size_t)(b * kS + q0 + w * 16 + hi * 4 + r)) * kD
              + h * 64 + n * 16 + lo] = f2bf(accO[n][r] * linv[r]);
}

// ---------------------------------------------------------------------------
// out = LayerNorm(a + r), all bf16; wave-per-row, ushort4 loads
// ---------------------------------------------------------------------------
__global__ __launch_bounds__(256) void add_ln_bf(
    const u16* __restrict__ a, const u16* __restrict__ r,
    const float* __restrict__ g, const float* __restrict__ bt,
    u16* __restrict__ out)
{
    const int lane = threadIdx.x & 63;
    const size_t row = (size_t)blockIdx.x * 4 + (threadIdx.x >> 6);
    const ushort4* a4 = (const ushort4*)(a + row * kD);
    const ushort4* r4 = (const ushort4*)(r + row * kD);
    float v[3][4];
    float s = 0.f;
#pragma unroll
    for (int j = 0; j < 3; ++j) {
        const ushort4 av = a4[j * 64 + lane];
        const ushort4 rv = r4[j * 64 + lane];
        v[j][0] = b2f(av.x) + b2f(rv.x);
        v[j][1] = b2f(av.y) + b2f(rv.y);
        v[j][2] = b2f(av.z) + b2f(rv.z);
        v[j][3] = b2f(av.w) + b2f(rv.w);
        s += v[j][0] + v[j][1] + v[j][2] + v[j][3];
    }
#pragma unroll
    for (int off = 32; off; off >>= 1) s += __shfl_xor(s, off);
    const float mu = s * (1.f / 768.f);
    float vs = 0.f;
#pragma unroll
    for (int j = 0; j < 3; ++j)
#pragma unroll
        for (int e = 0; e < 4; ++e) {
            const float t0 = v[j][e] - mu;
            vs = fmaf(t0, t0, vs);
        }
#pragma unroll
    for (int off = 32; off; off >>= 1) vs += __shfl_xor(vs, off);
    const float rstd = rsqrtf(vs * (1.f / 768.f) + 1e-5f);
    const float4* g4 = (const float4*)g;
    const float4* b4 = (const float4*)bt;
#pragma unroll
    for (int j = 0; j < 3; ++j) {
        const float4 gv = g4[j * 64 + lane];
        const float4 bv = b4[j * 64 + lane];
        ushort4 o;
        o.x = f2bf((v[j][0] - mu) * rstd * gv.x + bv.x);
        o.y = f2bf((v[j][1] - mu) * rstd * gv.y + bv.y);
        o.z = f2bf((v[j][2] - mu) * rstd * gv.z + bv.z);
        o.w = f2bf((v[j][3] - mu) * rstd * gv.w + bv.w);
        ((ushort4*)(out + row * kD))[j * 64 + lane] = o;
    }
}

// ---------------------------------------------------------------------------
// mean over s (bf16 input): 2-stage deterministic reduction
// ---------------------------------------------------------------------------
__global__ __launch_bounds__(192) void mean_part_bf(
    const u16* __restrict__ x, float* __restrict__ mred)
{
    const int c = blockIdx.x, b = blockIdx.y;
    const int d = threadIdx.x * 4;
    const u16* base = x + ((size_t)b * kS + c * 32) * kD + d;
    float s0 = 0.f, s1 = 0.f, s2 = 0.f, s3 = 0.f;
#pragma unroll 8
    for (int t = 0; t < 32; ++t) {
        const ushort4 u = *(const ushort4*)(base + (size_t)t * kD);
        s0 += b2f(u.x); s1 += b2f(u.y); s2 += b2f(u.z); s3 += b2f(u.w);
    }
    float4 o; o.x = s0; o.y = s1; o.z = s2; o.w = s3;
    *(float4*)(mred + ((size_t)b * 64 + c) * kD + d) = o;
}

__global__ __launch_bounds__(256) void mean_fin(
    const float* __restrict__ mred, float* __restrict__ out)
{
    const int d = blockIdx.x * 256 + threadIdx.x;
    const int b = blockIdx.y;
    float s = 0.f;
#pragma unroll
    for (int c = 0; c < 64; ++c) s += mred[((size_t)b * 64 + c) * kD + d];
    out[b * kD + d] = s * (1.f / 2048.f);
}

// ---------------------------------------------------------------------------
// FALLBACK f32 kernels (used only if ws too small)
// ---------------------------------------------------------------------------
__global__ __launch_bounds__(256) void add_ln_f32(
    const float* __restrict__ a, const float* __restrict__ r,
    const float* __restrict__ g, const float* __restrict__ bt,
    float* __restrict__ out)
{
    const int lane = threadIdx.x & 63;
    const size_t row = (size_t)blockIdx.x * 4 + (threadIdx.x >> 6);
    const float4* a4 = (const float4*)(a + row * kD);
    const float4* r4 = (const float4*)(r + row * kD);
    float4 v[3];
    float s = 0.f;
#pragma unroll
    for (int j = 0; j < 3; ++j) {
        const float4 av = a4[j * 64 + lane];
        const float4 rv = r4[j * 64 + lane];
        v[j].x = av.x + rv.x; v[j].y = av.y + rv.y;
        v[j].z = av.z + rv.z; v[j].w = av.w + rv.w;
        s += v[j].x + v[j].y + v[j].z + v[j].w;
    }
#pragma unroll
    for (int off = 32; off; off >>= 1) s += __shfl_xor(s, off);
    const float mu = s * (1.f / 768.f);
    float vs = 0.f;
#pragma unroll
    for (int j = 0; j < 3; ++j) {
        float t0 = v[j].x - mu, t1 = v[j].y - mu, t2 = v[j].z - mu, t3 = v[j].w - mu;
        vs = fmaf(t0, t0, fmaf(t1, t1, fmaf(t2, t2, fmaf(t3, t3, vs))));
    }
#pragma unroll
    for (int off = 32; off; off >>= 1) vs += __shfl_xor(vs, off);
    const float rstd = rsqrtf(vs * (1.f / 768.f) + 1e-5f);
    const float4* g4 = (const float4*)g;
    const float4* b4 = (const float4*)bt;
#pragma unroll
    for (int j = 0; j < 3; ++j) {
        const float4 gv = g4[j * 64 + lane];
        const float4 bv = b4[j * 64 + lane];
        float4 o;
        o.x = (v[j].x - mu) * rstd * gv.x + bv.x;
        o.y = (v[j].y - mu) * rstd * gv.y + bv.y;
        o.z = (v[j].z - mu) * rstd * gv.z + bv.z;
        o.w = (v[j].w - mu) * rstd * gv.w + bv.w;
        ((float4*)(out + row * kD))[j * 64 + lane] = o;
    }
}

__global__ __launch_bounds__(256) void mean_s(
    const float* __restrict__ x, float* __restrict__ out)
{
    const int d = blockIdx.x * 256 + threadIdx.x;
    const int b = blockIdx.y;
    float s = 0.f;
    for (int t = 0; t < kS; ++t) s += x[((size_t)b * kS + t) * kD + d];
    out[b * kD + d] = s * (1.f / 2048.f);
}

__global__ __launch_bounds__(256) void gemm_f32(
    const float* __restrict__ A, const float* __restrict__ W,
    const float* __restrict__ bias, float* __restrict__ C,
    int M, int N, int K, int relu)
{
    __shared__ float As[16][68];
    __shared__ float Bs[16][68];
    const int tid = threadIdx.x;
    const int row0 = blockIdx.x << 6;
    const int col0 = blockIdx.y << 6;
    const int tx = tid & 15, ty = tid >> 4;
    const int ar = tid >> 2;
    const int ak = (tid & 3) << 2;
    const int bk = tid >> 4;
    const int bc = (tid & 15) << 2;
    float acc[4][4] = {};
    const float* Ap = A + (size_t)(row0 + ar) * K + ak;
    const float* Wp = W + (size_t)bk * N + col0 + bc;
    for (int k0 = 0; k0 < K; k0 += 16) {
        const float4 a4 = *(const float4*)(Ap + k0);
        const float4 b4 = *(const float4*)(Wp + (size_t)k0 * N);
        __syncthreads();
        As[ak + 0][ar] = a4.x; As[ak + 1][ar] = a4.y;
        As[ak + 2][ar] = a4.z; As[ak + 3][ar] = a4.w;
        *(float4*)&Bs[bk][bc] = b4;
        __syncthreads();
#pragma unroll
        for (int kk = 0; kk < 16; ++kk) {
            const float4 av = *(const float4*)&As[kk][ty << 2];
            const float4 bv = *(const float4*)&Bs[kk][tx << 2];
            const float aa[4] = {av.x, av.y, av.z, av.w};
            const float bb[4] = {bv.x, bv.y, bv.z, bv.w};
#pragma unroll
            for (int i = 0; i < 4; ++i)
#pragma unroll
                for (int j = 0; j < 4; ++j)
                    acc[i][j] = fmaf(aa[i], bb[j], acc[i][j]);
        }
    }
#pragma unroll
    for (int i = 0; i < 4; ++i) {
        const int row = row0 + (ty << 2) + i;
#pragma unroll
        for (int j = 0; j < 4; ++j) {
            const int col = col0 + (tx << 2) + j;
            float v = acc[i][j] + bias[col];
            if (relu) v = fmaxf(v, 0.f);
            C[(size_t)row * N + col] = v;
        }
    }
}

__global__ __launch_bounds__(256) void attn_fused(
    const float* __restrict__ Q, const float* __restrict__ Km,
    const float* __restrict__ Vm, const int* __restrict__ ids,
    float* __restrict__ O)
{
    __shared__ float Ksf[64 * 64];
    __shared__ float Vtf[64 * 64];
    __shared__ float Qs[16][64];
    __shared__ float Psf[4][4][64];
    const int tid = threadIdx.x;
    const int w = tid >> 6;
    const int lane = tid & 63;
    const int h = blockIdx.y, b = blockIdx.z;
    const int qrow0 = blockIdx.x << 4;
    {
        const int r = tid >> 4;
        const int c4 = tid & 15;
        const float4 q4 = *(const float4*)(
            Q + ((size_t)(b * kS + qrow0 + r)) * kD + h * 64 + (c4 << 2));
        Qs[r][(c4 << 2) + 0] = q4.x * 0.125f;
        Qs[r][(c4 << 2) + 1] = q4.y * 0.125f;
        Qs[r][(c4 << 2) + 2] = q4.z * 0.125f;
        Qs[r][(c4 << 2) + 3] = q4.w * 0.125f;
    }
    float m[4], lsum[4], o[4];
#pragma unroll
    for (int r = 0; r < 4; ++r) { m[r] = -3.0e38f; lsum[r] = 0.f; o[r] = 0.f; }
    for (int kt = 0; kt < kS / 64; ++kt) {
        __syncthreads();
#pragma unroll
        for (int i = 0; i < 4; ++i) {
            const int lin = tid + (i << 8);
            const int row = lin >> 4;
            const int s4 = lin & 15;
            const size_t gro = ((size_t)(b * kS + (kt << 6) + row)) * kD + h * 64 + (s4 << 2);
            const float4 k4 = *(const float4*)(Km + gro);
            ((float4*)Ksf)[(row << 4) + (s4 ^ (row & 7))] = k4;
            const float4 v4 = *(const float4*)(Vm + gro);
            const int ksl = row >> 2, ke = row & 3;
            const int d0 = s4 << 2;
            Vtf[(d0 + 0) * 64 + ((ksl ^ ((d0 + 0) & 7)) << 2) + ke] = v4.x;
            Vtf[(d0 + 1) * 64 + ((ksl ^ ((d0 + 1) & 7)) << 2) + ke] = v4.y;
            Vtf[(d0 + 2) * 64 + ((ksl ^ ((d0 + 2) & 7)) << 2) + ke] = v4.z;
            Vtf[(d0 + 3) * 64 + ((ksl ^ ((d0 + 3) & 7)) << 2) + ke] = v4.w;
        }
        __syncthreads();
        const bool masked = (ids[(size_t)b * kS + (kt << 6) + lane] == 1);
        float scr[4] = {0.f, 0.f, 0.f, 0.f};
#pragma unroll
        for (int i16 = 0; i16 < 16; ++i16) {
            const float4 kv = ((const float4*)Ksf)[(lane << 4) + (i16 ^ (lane & 7))];
#pragma unroll
            for (int r = 0; r < 4; ++r) {
                const float4 qv = *(const float4*)&Qs[(w << 2) + r][i16 << 2];
                scr[r] = fmaf(kv.x, qv.x, fmaf(kv.y, qv.y,
                          fmaf(kv.z, qv.z, fmaf(kv.w, qv.w, scr[r]))));
            }
        }
#pragma unroll
        for (int r = 0; r < 4; ++r) {
            float sm = masked ? -3.0e38f : scr[r];
#pragma unroll
            for (int off = 32; off; off >>= 1) sm = fmaxf(sm, __shfl_xor(sm, off));
            const float mn = fmaxf(m[r], sm);
            const float cr = __expf(m[r] - mn);
            const float pv = masked ? 0.f : __expf(scr[r] - mn);
            float ps = pv;
#pragma unroll
            for (int off = 32; off; off >>= 1) ps += __shfl_xor(ps, off);
            lsum[r] = lsum[r] * cr + ps;
            o[r] *= cr;
            m[r] = mn;
            Psf[w][r][lane] = pv;
        }
#pragma unroll
        for (int i16 = 0; i16 < 16; ++i16) {
            const float4 vv = ((const float4*)Vtf)[(lane << 4) + (i16 ^ (lane & 7))];
#pragma unroll
            for (int r = 0; r < 4; ++r) {
                const float4 pv = *(const float4*)&Psf[w][r][i16 << 2];
                o[r] = fmaf(pv.x, vv.x, fmaf(pv.y, vv.y,
                        fmaf(pv.z, vv.z, fmaf(pv.w, vv.w, o[r]))));
            }
        }
    }
#pragma unroll
    for (int r = 0; r < 4; ++r)
        O[((size_t)(b * kS + qrow0 + (w << 2) + r)) * kD + h * 64 + lane] =
            o[r] / lsum[r];
}

// ---------------------------------------------------------------------------
// Host orchestration
// ---------------------------------------------------------------------------
extern "C" void kernel_launch(void* const* d_in, const int* in_sizes, int n_in,
                              void* d_out, int out_size, void* d_ws, size_t ws_size,
                              hipStream_t stream)
{
    const int*   ids   = (const int*)  d_in[0];
    const float* emb   = (const float*)d_in[1];
    const float* Wq    = (const float*)d_in[2];
    const float* bq    = (const float*)d_in[3];
    const float* Wk    = (const float*)d_in[4];
    const float* bk    = (const float*)d_in[5];
    const float* Wv    = (const float*)d_in[6];
    const float* bv    = (const float*)d_in[7];
    const float* Wo    = (const float*)d_in[8];
    const float* bo    = (const float*)d_in[9];
    const float* W1    = (const float*)d_in[10];
    const float* b1    = (const float*)d_in[11];
    const float* W2    = (const float*)d_in[12];
    const float* b2    = (const float*)d_in[13];
    const float* gamma = (const float*)d_in[14];
    const float* beta  = (const float*)d_in[15];
    float* out = (float*)d_out;

    const size_t BUFE = (size_t)kB * kS * kD;          // 6,291,456
    const size_t WDD  = (size_t)kD * kD;
    const size_t WDF  = (size_t)kD * kF;
    const size_t HIDE = (size_t)kB * kS * kF;          // hidden/qkv scratch elems
    const int NTOK = kB * kS;                          // 8192

    const size_t NEED = BUFE * 2 * 4                   // xb, x1b, ao, ob (bf16)
                      + HIDE * 2                       // shared qkv/hidden scratch
                      + WARENA_E * 2                   // weight arena
                      + (size_t)6 * 6912 * 4           // bias arena
                      + 128 * 8                        // mask bits
                      + (size_t)kB * 64 * kD * 4;      // mean partials

    if (ws_size >= NEED) {
        u16*   xb  = (u16*)d_ws;                       // residual stream (bf16)
        u16*   x1b = xb + BUFE;
        u16*   ao  = x1b + BUFE;                       // attn out
        u16*   ob  = ao + BUFE;                        // proj/ffn out
        u16*   sc  = ob + BUFE;                        // qkv AND ffn-hidden
        u16*   vtb = sc + (size_t)NTOK * kQW;          // vT aliases sc tail
        u16*   wa  = sc + HIDE;
        float* ba  = (float*)(wa + WARENA_E);
        u64*   mbt = (u64*)(ba + 6 * 6912);
        float* mrd = (float*)(mbt + 128);

        embed_pe<<<NTOK, 256, 0, stream>>>(ids, emb, xb);
        mk_maskbits<<<kB * kS / 64, 64, 0, stream>>>(ids, mbt);
        bias_build<<<(6 * 6912 + 255) / 256, 256, 0, stream>>>(
            bq, bk, bv, bo, b1, b2, ba);

        for (int l = 0; l < kL; ++l) {
            const size_t oDD = (size_t)l * WDD;
            const size_t oDF = (size_t)l * WDF;
            const float* bl = ba + (size_t)l * 6912;
            const float* gl  = gamma + (size_t)l * kD;
            const float* btl = beta  + (size_t)l * kD;

            cvt_all<<<1728, 256, 0, stream>>>(
                Wq + oDD, Wk + oDD, Wv + oDD, Wo + oDD, W1 + oDF, W2 + oDF, wa);

            // fused QKV (Q pre-scaled); V -> permuted vT
            gemm256b<<<dim3(64, 9), 256, 0, stream>>>(
                xb, wa, bl, sc, vtb, NTOK, kQW, kD, 3);

            attn_mfma<<<dim3(kS / 128, kH, kB), 512, 0, stream>>>(
                sc, vtb, mbt, ao);

            gemm_bf16<<<dim3(64, 6), 256, 0, stream>>>(
                ao, wa + OFF_WO, bl + 2304, ob, nullptr, NTOK, kD, kD, 1);

            // x1 = LN(x + o)
            add_ln_bf<<<NTOK / 4, 256, 0, stream>>>(xb, ob, gl, btl, x1b);

            // FFN: hidden -> sc, down-proj
            gemm256b<<<dim3(64, 12), 256, 0, stream>>>(
                x1b, wa + OFF_W1, bl + 3072, sc, nullptr, NTOK, kF, kD, 2);
            gemm_bf16<<<dim3(64, 6), 256, 0, stream>>>(
                sc, wa + OFF_W2, bl + 6144, ob, nullptr, NTOK, kD, kF, 1);

            // x = LN(x1 + ffn)
            add_ln_bf<<<NTOK / 4, 256, 0, stream>>>(x1b, ob, gl, btl, xb);
        }

        mean_part_bf<<<dim3(64, kB), 192, 0, stream>>>(xb, mrd);
        mean_fin<<<dim3(kD / 256, kB), 256, 0, stream>>>(mrd, out);
        return;
    }

    // -------- fallback f32 path --------
    if (ws_size < 5 * BUFE * sizeof(float)) return;
    float* xb = (float*)d_ws;
    float* kb = xb + BUFE;
    float* qb = kb + BUFE;
    float* vb = qb + BUFE;
    float* obf = vb + BUFE;
    float* hb = qb;

    embed_pe_f32<<<NTOK, 256, 0, stream>>>(ids, emb, xb);
    for (int l = 0; l < kL; ++l) {
        const size_t oDD = (size_t)l * WDD;
        const size_t oDF = (size_t)l * WDF;
        gemm_f32<<<dim3(NTOK / 64, kD / 64), 256, 0, stream>>>(
            xb, Wq + oDD, bq + (size_t)l * kD, qb, NTOK, kD, kD, 0);
        gemm_f32<<<dim3(NTOK / 64, kD / 64), 256, 0, stream>>>(
            xb, Wk + oDD, bk + (size_t)l * kD, kb, NTOK, kD, kD, 0);
        gemm_f32<<<dim3(NTOK / 64, kD / 64), 256, 0, stream>>>(
            xb, Wv + oDD, bv + (size_t)l * kD, vb, NTOK, kD, kD, 0);
        attn_fused<<<dim3(kS / 16, kH, kB), 256, 0, stream>>>(qb, kb, vb, ids, obf);
        gemm_f32<<<dim3(NTOK / 64, kD / 64), 256, 0, stream>>>(
            obf, Wo + oDD, bo + (size_t)l * kD, qb, NTOK, kD, kD, 0);
        add_ln_f32<<<NTOK / 4, 256, 0, stream>>>(xb, qb,
            gamma + (size_t)l * kD, beta + (size_t)l * kD, kb);
        for (int c = 0; c < 2; ++c) {
            const size_t ro = (size_t)c * 4096;
            gemm_f32<<<dim3(4096 / 64, kF / 64), 256, 0, stream>>>(
                kb + ro * kD, W1 + oDF, b1 + (size_t)l * kF, hb, 4096, kF, kD, 1);
            gemm_f32<<<dim3(4096 / 64, kD / 64), 256, 0, stream>>>(
                hb, W2 + oDF, b2 + (size_t)l * kD, obf + ro * kD, 4096, kD, kF, 0);
        }
        add_ln_f32<<<NTOK / 4, 256, 0, stream>>>(kb, obf,
            gamma + (size_t)l * kD, beta + (size_t)l * kD, xb);
    }
    mean_s<<<dim3(kD / 256, kB), 256, 0, stream>>>(xb, out);
}

// Round 12
// 1479.718 us; speedup vs baseline: 1.0329x; 1.0329x over previous
//
#include <hip/hip_runtime.h>
#include <hip/hip_bf16.h>
#include <math.h>

typedef unsigned short u16;
typedef unsigned long long u64;
using bf16x8 = __attribute__((ext_vector_type(8))) short;
using f32x4  = __attribute__((ext_vector_type(4))) float;

static constexpr int kD = 768;
static constexpr int kH = 12;
static constexpr int kL = 6;
static constexpr int kF = 3072;
static constexpr int kS = 2048;
static constexpr int kB = 4;
static constexpr int kQW = 2304;          // fused QKV width
static constexpr int kNT = kB * kS;       // 8192 tokens

// Q prescale: 1/sqrt(64) * log2(e)  -> scores come out in log2 units
static constexpr float kQScale = 0.18033688011112043f;

__device__ __forceinline__ u16 f2bf(float f) {
    return __bfloat16_as_ushort(__float2bfloat16(f));
}
__device__ __forceinline__ float b2f(u16 u) {
    return __uint_as_float((unsigned)u << 16);
}
__device__ __forceinline__ unsigned cvtpk(float a, float b) {
    unsigned d;
    asm volatile("v_cvt_pk_bf16_f32 %0, %1, %2" : "=v"(d) : "v"(a), "v"(b));
    return d;
}
__device__ __forceinline__ float exp2fast(float x) {
#if __has_builtin(__builtin_amdgcn_exp2f)
    return __builtin_amdgcn_exp2f(x);
#else
    return __expf(x * 0.6931471805599453f);
#endif
}

__device__ __forceinline__ void gload16(const void* g, void* l) {
    auto gp = reinterpret_cast<const __attribute__((address_space(1))) unsigned int*>(
        reinterpret_cast<uintptr_t>(g));
    auto lp = reinterpret_cast<__attribute__((address_space(3))) unsigned int*>(
        reinterpret_cast<uintptr_t>(l));
    __builtin_amdgcn_global_load_lds(gp, lp, 16, 0, 0);
}

// ---------------------------------------------------------------------------
// Embedding + sinusoidal PE -> bf16 residual stream
// ---------------------------------------------------------------------------
__global__ __launch_bounds__(256) void embed_pe(
    const int* __restrict__ ids, const float* __restrict__ emb,
    u16* __restrict__ xbf)
{
    const int t = blockIdx.x;
    const int s = t & (kS - 1);
    const int id = ids[t];
#pragma unroll
    for (int j = 0; j < 3; ++j) {
        const int d = threadIdx.x + (j << 8);
        const float i2 = (float)((d >> 1) << 1);
        const float dv = __expf(i2 * (-9.210340371976184f / 768.f));
        const float ang = (float)s * dv;
        const float pe = (d & 1) ? cosf(ang) : sinf(ang);
        xbf[(size_t)t * kD + d] = f2bf(emb[(size_t)id * kD + d] + pe);
    }
}

__global__ __launch_bounds__(256) void embed_pe_f32(
    const int* __restrict__ ids, const float* __restrict__ emb,
    float* __restrict__ x)
{
    const int t = blockIdx.x;
    const int s = t & (kS - 1);
    const int id = ids[t];
#pragma unroll
    for (int j = 0; j < 3; ++j) {
        const int d = threadIdx.x + (j << 8);
        const float i2 = (float)((d >> 1) << 1);
        const float dv = __expf(i2 * (-9.210340371976184f / 768.f));
        const float ang = (float)s * dv;
        const float pe = (d & 1) ? cosf(ang) : sinf(ang);
        x[(size_t)t * kD + d] = emb[(size_t)id * kD + d] + pe;
    }
}

// mask bitmask: bit k of word (b*32+kt) = (ids[b*2048+kt*64+k] != 1)
__global__ __launch_bounds__(64) void mk_maskbits(const int* __restrict__ ids,
                                                  u64* __restrict__ mbits)
{
    const int w = blockIdx.x;
    const int lane = threadIdx.x;
    const u64 m = __ballot(ids[(size_t)w * 64 + lane] != 1);
    if (lane == 0) mbits[w] = m;
}

// bias arena: per layer 6912 floats: [qkv(bq*kQScale|bk|bv) | bo | b1 | b2]
__global__ __launch_bounds__(256) void bias_build(
    const float* __restrict__ bq, const float* __restrict__ bk,
    const float* __restrict__ bv, const float* __restrict__ bo,
    const float* __restrict__ b1, const float* __restrict__ b2,
    float* __restrict__ ba)
{
    const int i = blockIdx.x * 256 + threadIdx.x;
    if (i >= 6 * 6912) return;
    const int l = i / 6912, p = i % 6912;
    float v;
    if      (p < 768)  v = bq[l * 768 + p] * kQScale;
    else if (p < 1536) v = bk[l * 768 + p - 768];
    else if (p < 2304) v = bv[l * 768 + p - 1536];
    else if (p < 3072) v = bo[l * 768 + p - 2304];
    else if (p < 6144) v = b1[(size_t)l * 3072 + p - 3072];
    else               v = b2[l * 768 + p - 6144];
    ba[i] = v;
}

// ---------------------------------------------------------------------------
// Per-layer weight converter: all 6 matrices -> transposed bf16 arena.
// ---------------------------------------------------------------------------
static constexpr size_t OFF_WO = (size_t)2304 * 768;
static constexpr size_t OFF_W1 = OFF_WO + (size_t)768 * 768;
static constexpr size_t OFF_W2 = OFF_W1 + (size_t)3072 * 768;
static constexpr size_t WARENA_E = OFF_W2 + (size_t)768 * 3072;

__global__ __launch_bounds__(256) void cvt_all(
    const float* __restrict__ Wq, const float* __restrict__ Wk,
    const float* __restrict__ Wv, const float* __restrict__ Wo,
    const float* __restrict__ W1, const float* __restrict__ W2,
    u16* __restrict__ wa)
{
    __shared__ float T[64][68];
    const int t = blockIdx.x;
    const float* S; u16* Dp; int Nsrc, Kdst, srow0, scol0; float sc = 1.f;
    if (t < 432) {
        const int ni = t % 36, ki = t / 36;
        const int ng = ni * 64;
        const int sel = ng / 768;
        scol0 = ng % 768; srow0 = ki * 64;
        S = (sel == 0) ? Wq : (sel == 1) ? Wk : Wv;
        if (sel == 0) sc = kQScale;
        Nsrc = 768; Kdst = 768;
        Dp = wa + (size_t)ng * 768 + srow0;
    } else if (t < 576) {
        const int tt = t - 432; const int ni = tt % 12, ki = tt / 12;
        scol0 = ni * 64; srow0 = ki * 64;
        S = Wo; Nsrc = 768; Kdst = 768;
        Dp = wa + OFF_WO + (size_t)(ni * 64) * 768 + srow0;
    } else if (t < 1152) {
        const int tt = t - 576; const int ni = tt % 48, ki = tt / 48;
        scol0 = ni * 64; srow0 = ki * 64;
        S = W1; Nsrc = 3072; Kdst = 768;
        Dp = wa + OFF_W1 + (size_t)(ni * 64) * 768 + srow0;
    } else {
        const int tt = t - 1152; const int ni = tt % 12, ki = tt / 12;
        scol0 = ni * 64; srow0 = ki * 64;
        S = W2; Nsrc = 768; Kdst = 3072;
        Dp = wa + OFF_W2 + (size_t)(ni * 64) * 3072 + srow0;
    }
    const int tid = threadIdx.x;
#pragma unroll
    for (int i = 0; i < 4; ++i) {
        const int idx = tid + (i << 8);
        const int kr = idx >> 4;
        const int nc = (idx & 15) << 2;
        const float4 v = *(const float4*)(S + (size_t)(srow0 + kr) * Nsrc + scol0 + nc);
        T[kr][nc] = v.x; T[kr][nc + 1] = v.y; T[kr][nc + 2] = v.z; T[kr][nc + 3] = v.w;
    }
    __syncthreads();
#pragma unroll
    for (int i = 0; i < 4; ++i) {
        const int idx = tid + (i << 8);
        const int nr = idx >> 4;
        const int kc = (idx & 15) << 2;
        ushort4 o;
        o.x = f2bf(T[kc][nr] * sc);     o.y = f2bf(T[kc + 1][nr] * sc);
        o.z = f2bf(T[kc + 2][nr] * sc); o.w = f2bf(T[kc + 3][nr] * sc);
        *(ushort4*)(Dp + (size_t)nr * Kdst + kc) = o;
    }
}

// ---------------------------------------------------------------------------
// gemm256b: 128x256 tile, BK=32, 4 waves, TRIPLE-buffered LDS (72KB),
// counted vmcnt(6), single barrier per K-step, 2 blocks/CU.
// mode: 1=bf16 out, 2=bf16+ReLU, 3=QKV (cols>=1536 -> permuted vT)
// ---------------------------------------------------------------------------
__global__ __launch_bounds__(256, 2) void gemm256b(
    const u16* __restrict__ A, const u16* __restrict__ Bt,
    const float* __restrict__ bias, void* __restrict__ Cv,
    u16* __restrict__ vTp, int M, int N, int K, int mode)
{
    __shared__ u16 As[3][4096];      // 128 rows x 32 K
    __shared__ u16 Bs[3][8192];      // 256 cols x 32 K
    const int tid = threadIdx.x;
    const int l = tid & 63;
    const int lo = l & 15, hi = l >> 4;
    const int wc = tid >> 6;         // 4 waves: 1 (M) x 4 (N)

    int brow = blockIdx.x, bcol = blockIdx.y;
    const int gx = gridDim.x;
    if ((gx & 7) == 0) {
        const int id = blockIdx.y * gx + blockIdx.x;
        const int xcd = id & 7, idx = id >> 3;
        const int rpx = gx >> 3;
        brow = xcd * rpx + (idx % rpx);
        bcol = idx / rpx;
    }
    const size_t row0 = (size_t)brow * 128;
    const size_t col0 = (size_t)bcol * 256;

    const int ca0 = tid, ca1 = tid + 256;
    const int ra0 = ca0 >> 2, ga0 = (ca0 & 3) ^ ((ra0 >> 1) & 3);
    const int ra1 = ca1 >> 2, ga1 = (ca1 & 3) ^ ((ra1 >> 1) & 3);
    const u16* aP0 = A + (row0 + ra0) * K + ga0 * 8;
    const u16* aP1 = A + (row0 + ra1) * K + ga1 * 8;
    const u16* bP[4];
#pragma unroll
    for (int q = 0; q < 4; ++q) {
        const int c = tid + (q << 8);
        const int r = c >> 2, g = (c & 3) ^ ((r >> 1) & 3);
        bP[q] = Bt + (col0 + r) * K + g * 8;
    }

    f32x4 acc[8][4];
#pragma unroll
    for (int i = 0; i < 8; ++i)
#pragma unroll
        for (int j = 0; j < 4; ++j)
#pragma unroll
            for (int r = 0; r < 4; ++r) acc[i][j][r] = 0.f;

    int aoff[8], boff[4];
#pragma unroll
    for (int i = 0; i < 8; ++i) {
        const int ra = i * 16 + lo;
        aoff[i] = ra * 32 + ((hi ^ ((ra >> 1) & 3)) << 3);
    }
#pragma unroll
    for (int j = 0; j < 4; ++j) {
        const int rb = wc * 64 + j * 16 + lo;
        boff[j] = rb * 32 + ((hi ^ ((rb >> 1) & 3)) << 3);
    }

    const int NT = K >> 5;
    // prologue: stage K-steps 0 and 1
#pragma unroll
    for (int t = 0; t < 2; ++t) {
        const int k0 = t << 5;
        gload16(aP0 + k0, As[t] + ca0 * 8);
        gload16(aP1 + k0, As[t] + ca1 * 8);
#pragma unroll
        for (int q = 0; q < 4; ++q)
            gload16(bP[q] + k0, Bs[t] + (tid + (q << 8)) * 8);
    }

    int cur = 0;
    for (int t = 0; t < NT; ++t) {
        if (t + 1 < NT) {
            asm volatile("s_waitcnt vmcnt(6)" ::: "memory");  // step t landed
        } else {
            asm volatile("s_waitcnt vmcnt(0)" ::: "memory");
        }
        __builtin_amdgcn_s_barrier();
        if (t + 2 < NT) {
            const int k0 = (t + 2) << 5;
            const int nb = (cur + 2 >= 3) ? cur - 1 : cur + 2;
            gload16(aP0 + k0, As[nb] + ca0 * 8);
            gload16(aP1 + k0, As[nb] + ca1 * 8);
#pragma unroll
            for (int q = 0; q < 4; ++q)
                gload16(bP[q] + k0, Bs[nb] + (tid + (q << 8)) * 8);
        }
        bf16x8 af[8], bfr[4];
#pragma unroll
        for (int i = 0; i < 8; ++i) af[i]  = *(const bf16x8*)&As[cur][aoff[i]];
#pragma unroll
        for (int j = 0; j < 4; ++j) bfr[j] = *(const bf16x8*)&Bs[cur][boff[j]];
        __builtin_amdgcn_s_setprio(1);
#pragma unroll
        for (int i = 0; i < 8; ++i)
#pragma unroll
            for (int j = 0; j < 4; ++j)
                acc[i][j] = __builtin_amdgcn_mfma_f32_16x16x32_bf16(
                    af[i], bfr[j], acc[i][j], 0, 0, 0);
        __builtin_amdgcn_s_setprio(0);
        cur = (cur + 1 == 3) ? 0 : cur + 1;
    }

    const bool vmode = (mode == 3) && (col0 >= 1536);
    if (vmode) {
#pragma unroll
        for (int i = 0; i < 8; ++i) {
            const size_t rbase = row0 + i * 16 + hi * 4;     // token, %4==0
            const size_t tb = (rbase >> 6) * 64;
            const int k0 = (int)(rbase & 63);
            const int pos = (((k0 >> 2) & 3) << 3) + (((k0 >> 4) & 1) << 2)
                          + ((k0 >> 5) << 5);
#pragma unroll
            for (int j = 0; j < 4; ++j) {
                const size_t c = col0 + wc * 64 + j * 16 + lo;
                const float bs = bias[c];
                const size_t d = c - 1536;
                ushort4 o;
                o.x = f2bf(acc[i][j][0] + bs);
                o.y = f2bf(acc[i][j][1] + bs);
                o.z = f2bf(acc[i][j][2] + bs);
                o.w = f2bf(acc[i][j][3] + bs);
                *(ushort4*)(vTp + d * (size_t)M + tb + pos) = o;
            }
        }
        return;
    }

#pragma unroll
    for (int i = 0; i < 8; ++i) {
        const size_t rbase = row0 + i * 16 + hi * 4;
#pragma unroll
        for (int j = 0; j < 4; ++j) {
            const size_t c = col0 + wc * 64 + j * 16 + lo;
            const float bs = bias[c];
#pragma unroll
            for (int r = 0; r < 4; ++r) {
                float v = acc[i][j][r] + bs;
                if (mode == 2) v = fmaxf(v, 0.f);
                ((u16*)Cv)[(rbase + r) * (size_t)N + c] = f2bf(v);
            }
        }
    }
}

// ---------------------------------------------------------------------------
// gemm_bf16: 128x128 tile (WO / FFN2), TRIPLE-buffered (48KB LDS),
// counted vmcnt(4), single barrier per K-step.
// ---------------------------------------------------------------------------
__global__ __launch_bounds__(256) void gemm_bf16(
    const u16* __restrict__ A, const u16* __restrict__ Bt,
    const float* __restrict__ bias, void* __restrict__ Cv,
    u16* __restrict__ vTp, int M, int N, int K, int mode)
{
    __shared__ u16 As[3][4096];
    __shared__ u16 Bs[3][4096];
    const int tid = threadIdx.x;
    const int l = tid & 63;
    const int lo = l & 15, hi = l >> 4;
    const int w = tid >> 6, wr = w >> 1, wc = w & 1;

    int brow = blockIdx.x, bcol = blockIdx.y;
    const int gx = gridDim.x;
    if ((gx & 7) == 0) {
        const int id = blockIdx.y * gx + blockIdx.x;
        const int xcd = id & 7, idx = id >> 3;
        const int rpx = gx >> 3;
        brow = xcd * rpx + (idx % rpx);
        bcol = idx / rpx;
    }
    const size_t row0 = (size_t)brow * 128;
    const size_t col0 = (size_t)bcol * 128;

    const int c0 = tid, c1 = tid + 256;
    const int r0 = c0 >> 2, g0 = (c0 & 3) ^ ((r0 >> 1) & 3);
    const int r1 = c1 >> 2, g1 = (c1 & 3) ^ ((r1 >> 1) & 3);
    const u16* a0 = A  + (row0 + r0) * K + g0 * 8;
    const u16* a1 = A  + (row0 + r1) * K + g1 * 8;
    const u16* b0 = Bt + (col0 + r0) * K + g0 * 8;
    const u16* b1 = Bt + (col0 + r1) * K + g1 * 8;

    f32x4 acc[4][4];
#pragma unroll
    for (int i = 0; i < 4; ++i)
#pragma unroll
        for (int j = 0; j < 4; ++j)
#pragma unroll
            for (int r = 0; r < 4; ++r) acc[i][j][r] = 0.f;

    int aoff[4], boff[4];
#pragma unroll
    for (int i = 0; i < 4; ++i) {
        const int ra = wr * 64 + i * 16 + lo;
        aoff[i] = ra * 32 + ((hi ^ ((ra >> 1) & 3)) << 3);
        const int rb = wc * 64 + i * 16 + lo;
        boff[i] = rb * 32 + ((hi ^ ((rb >> 1) & 3)) << 3);
    }

    const int NT = K >> 5;
    // prologue: stage K-steps 0 and 1
#pragma unroll
    for (int t = 0; t < 2; ++t) {
        const int k0 = t << 5;
        gload16(a0 + k0, As[t] + c0 * 8);
        gload16(a1 + k0, As[t] + c1 * 8);
        gload16(b0 + k0, Bs[t] + c0 * 8);
        gload16(b1 + k0, Bs[t] + c1 * 8);
    }

    int cur = 0;
    for (int t = 0; t < NT; ++t) {
        if (t + 1 < NT) {
            asm volatile("s_waitcnt vmcnt(4)" ::: "memory");  // step t landed
        } else {
            asm volatile("s_waitcnt vmcnt(0)" ::: "memory");
        }
        __builtin_amdgcn_s_barrier();
        if (t + 2 < NT) {
            const int k0 = (t + 2) << 5;
            const int nb = (cur + 2 >= 3) ? cur - 1 : cur + 2;
            gload16(a0 + k0, As[nb] + c0 * 8);
            gload16(a1 + k0, As[nb] + c1 * 8);
            gload16(b0 + k0, Bs[nb] + c0 * 8);
            gload16(b1 + k0, Bs[nb] + c1 * 8);
        }
        bf16x8 af[4], bfr[4];
#pragma unroll
        for (int i = 0; i < 4; ++i) af[i]  = *(const bf16x8*)&As[cur][aoff[i]];
#pragma unroll
        for (int j = 0; j < 4; ++j) bfr[j] = *(const bf16x8*)&Bs[cur][boff[j]];
        __builtin_amdgcn_s_setprio(1);
#pragma unroll
        for (int i = 0; i < 4; ++i)
#pragma unroll
            for (int j = 0; j < 4; ++j)
                acc[i][j] = __builtin_amdgcn_mfma_f32_16x16x32_bf16(
                    af[i], bfr[j], acc[i][j], 0, 0, 0);
        __builtin_amdgcn_s_setprio(0);
        cur = (cur + 1 == 3) ? 0 : cur + 1;
    }

#pragma unroll
    for (int i = 0; i < 4; ++i) {
        const size_t rbase = row0 + wr * 64 + i * 16 + hi * 4;
#pragma unroll
        for (int j = 0; j < 4; ++j) {
            const size_t c = col0 + wc * 64 + j * 16 + lo;
            const float bs = bias[c];
#pragma unroll
            for (int r = 0; r < 4; ++r) {
                float v = acc[i][j][r] + bs;
                if (mode == 2) v = fmaxf(v, 0.f);
                ((u16*)Cv)[(rbase + r) * (size_t)N + c] = f2bf(v);
            }
        }
    }
}

// ---------------------------------------------------------------------------
// MFMA flash attention v9 — 128-key pairs per iteration (merged softmax:
// one rmax reduce / skip / rescale / barrier / vmcnt per 128 keys),
// 4 LDS buffers with opposite-parity prefetch, deferred lsum reduction.
// Grid (S/128, H, B) flat-swizzled; 512 threads.
// ---------------------------------------------------------------------------
__global__ __launch_bounds__(512) void attn_mfma(
    const u16* __restrict__ QKV, const u16* __restrict__ vT,
    const u64* __restrict__ mbits, u16* __restrict__ O)
{
    __shared__ u16 Ks[4][4096];   // [key][64 d], slot-swizzled
    __shared__ u16 Vs[4][4096];   // [d][64 pos], slot-swizzled

    const int tid = threadIdx.x, l = tid & 63, w = tid >> 6;
    const int lo = l & 15, hi = l >> 4;

    const int flat = blockIdx.x + 16 * (blockIdx.y + 12 * blockIdx.z);
    const int nf = (flat & 7) * 96 + (flat >> 3);
    const int qi = nf & 15;
    const int h  = (nf >> 4) % 12;
    const int b  = nf / 192;
    const int q0 = qi << 7;

    bf16x8 qf0, qf1;
    {
        const u16* qp = QKV + ((size_t)(b * kS + q0 + w * 16 + lo)) * kQW
                            + h * 64 + hi * 8;
        qf0 = *(const bf16x8*)qp;
        qf1 = *(const bf16x8*)(qp + 32);
    }

    const int rw = tid >> 3, sx = tid & 7, E = sx ^ (rw & 7);
    const u16* Kbase = QKV + (size_t)(b * kS) * kQW + 768 + h * 64;
    const u16* Vbase = vT + (size_t)(h * 64) * kNT + b * kS;

    f32x4 accO[4];
#pragma unroll
    for (int n = 0; n < 4; ++n)
#pragma unroll
        for (int r = 0; r < 4; ++r) accO[n][r] = 0.f;
    float m = -3.0e38f, lsum = 0.f;   // lsum = per-lane partial (reduced at end)

    const int ksw = (lo & 7) << 3;
    constexpr int NP = kS / 128;      // 16 pairs

    // prologue: stage pair 0 (tiles 0,1 -> buffers 0,1)
#pragma unroll
    for (int t = 0; t < 2; ++t) {
        const size_t kof = (size_t)(t << 6) * kQW;
        const size_t vof = (size_t)(t << 6);
        gload16(Kbase + kof + (size_t)rw * kQW + E * 8, Ks[t] + tid * 8);
        gload16(Vbase + (size_t)rw * kNT + vof + E * 8, Vs[t] + tid * 8);
    }

    for (int it = 0; it < NP; ++it) {
        const int bA = (it & 1) << 1, bB = bA + 1;
        asm volatile("s_waitcnt vmcnt(0)" ::: "memory");
        __syncthreads();

        // prefetch pair it+1 into opposite-parity buffers
        if (it + 1 < NP) {
            const int nA = ((it + 1) & 1) << 1, nB = nA + 1;
            const size_t kofA = (size_t)((2 * it + 2) << 6) * kQW;
            const size_t kofB = (size_t)((2 * it + 3) << 6) * kQW;
            const size_t vofA = (size_t)((2 * it + 2) << 6);
            const size_t vofB = (size_t)((2 * it + 3) << 6);
            gload16(Kbase + kofA + (size_t)rw * kQW + E * 8, Ks[nA] + tid * 8);
            gload16(Vbase + (size_t)rw * kNT + vofA + E * 8, Vs[nA] + tid * 8);
            gload16(Kbase + kofB + (size_t)rw * kQW + E * 8, Ks[nB] + tid * 8);
            gload16(Vbase + (size_t)rw * kNT + vofB + E * 8, Vs[nB] + tid * 8);
        }

        // ---- scores for both sub-tiles (log2 units) ----
        f32x4 stA[4], stB[4];
        __builtin_amdgcn_s_setprio(1);
#pragma unroll
        for (int j = 0; j < 4; ++j) {
#pragma unroll
            for (int r = 0; r < 4; ++r) { stA[j][r] = 0.f; stB[j][r] = 0.f; }
            const int kb2 = (j * 16 + lo) * 64;
            const bf16x8 a0 = *(const bf16x8*)&Ks[bA][kb2 + ((hi * 8)      ^ ksw)];
            const bf16x8 a1 = *(const bf16x8*)&Ks[bA][kb2 + ((hi * 8 + 32) ^ ksw)];
            const bf16x8 b0v = *(const bf16x8*)&Ks[bB][kb2 + ((hi * 8)      ^ ksw)];
            const bf16x8 b1v = *(const bf16x8*)&Ks[bB][kb2 + ((hi * 8 + 32) ^ ksw)];
            stA[j] = __builtin_amdgcn_mfma_f32_16x16x32_bf16(a0, qf0, stA[j], 0, 0, 0);
            stA[j] = __builtin_amdgcn_mfma_f32_16x16x32_bf16(a1, qf1, stA[j], 0, 0, 0);
            stB[j] = __builtin_amdgcn_mfma_f32_16x16x32_bf16(b0v, qf0, stB[j], 0, 0, 0);
            stB[j] = __builtin_amdgcn_mfma_f32_16x16x32_bf16(b1v, qf1, stB[j], 0, 0, 0);
        }
        __builtin_amdgcn_s_setprio(0);

        // ---- merged online softmax over 128 keys, row = q = lo ----
        float rmax = stA[0][0];
#pragma unroll
        for (int j = 0; j < 4; ++j)
#pragma unroll
            for (int r = 0; r < 4; ++r) {
                rmax = fmaxf(rmax, stA[j][r]);
                rmax = fmaxf(rmax, stB[j][r]);
            }
        rmax = fmaxf(rmax, __shfl_xor(rmax, 16));
        rmax = fmaxf(rmax, __shfl_xor(rmax, 32));

        const bool skip = __all(rmax <= m + 11.0f);
        if (!skip) {
            const float mn = fmaxf(m, rmax);
            const float corr = exp2fast(m - mn);
            m = mn;
            lsum *= corr;
            float c2[4];
#pragma unroll
            for (int r = 0; r < 4; ++r) c2[r] = __shfl(corr, hi * 4 + r);
#pragma unroll
            for (int n = 0; n < 4; ++n)
#pragma unroll
                for (int r = 0; r < 4; ++r) accO[n][r] *= c2[r];
        }

#pragma unroll
        for (int j = 0; j < 4; ++j)
#pragma unroll
            for (int r = 0; r < 4; ++r) {
                stA[j][r] = exp2fast(stA[j][r] - m);
                stB[j][r] = exp2fast(stB[j][r] - m);
            }

        const u64 mbA = mbits[b * 32 + 2 * it];
        const u64 mbB = mbits[b * 32 + 2 * it + 1];
        if (mbA != ~0ull) {
#pragma unroll
            for (int j = 0; j < 4; ++j)
#pragma unroll
                for (int r = 0; r < 4; ++r)
                    if (!((mbA >> (j * 16 + hi * 4 + r)) & 1)) stA[j][r] = 0.f;
        }
        if (mbB != ~0ull) {
#pragma unroll
            for (int j = 0; j < 4; ++j)
#pragma unroll
                for (int r = 0; r < 4; ++r)
                    if (!((mbB >> (j * 16 + hi * 4 + r)) & 1)) stB[j][r] = 0.f;
        }

        // per-lane partial sum (deferred cross-lane reduction)
        float ts = 0.f;
#pragma unroll
        for (int j = 0; j < 4; ++j)
#pragma unroll
            for (int r = 0; r < 4; ++r) ts += stA[j][r] + stB[j][r];
        lsum += ts;

        // ---- pack P (k-slot order matches vT's pos()) ----
        union PU { unsigned u[4]; bf16x8 v; } p0, p1, p2, p3;
        p0.u[0] = cvtpk(stA[0][0], stA[0][1]); p0.u[1] = cvtpk(stA[0][2], stA[0][3]);
        p0.u[2] = cvtpk(stA[1][0], stA[1][1]); p0.u[3] = cvtpk(stA[1][2], stA[1][3]);
        p1.u[0] = cvtpk(stA[2][0], stA[2][1]); p1.u[1] = cvtpk(stA[2][2], stA[2][3]);
        p1.u[2] = cvtpk(stA[3][0], stA[3][1]); p1.u[3] = cvtpk(stA[3][2], stA[3][3]);
        p2.u[0] = cvtpk(stB[0][0], stB[0][1]); p2.u[1] = cvtpk(stB[0][2], stB[0][3]);
        p2.u[2] = cvtpk(stB[1][0], stB[1][1]); p2.u[3] = cvtpk(stB[1][2], stB[1][3]);
        p3.u[0] = cvtpk(stB[2][0], stB[2][1]); p3.u[1] = cvtpk(stB[2][2], stB[2][3]);
        p3.u[2] = cvtpk(stB[3][0], stB[3][1]); p3.u[3] = cvtpk(stB[3][2], stB[3][3]);

        // ---- PV over both sub-tiles ----
        __builtin_amdgcn_s_setprio(1);
#pragma unroll
        for (int n = 0; n < 4; ++n) {
            const int vb2 = (n * 16 + lo) * 64;
            const bf16x8 vA0 = *(const bf16x8*)&Vs[bA][vb2 + ((hi * 8)      ^ ksw)];
            const bf16x8 vA1 = *(const bf16x8*)&Vs[bA][vb2 + ((hi * 8 + 32) ^ ksw)];
            const bf16x8 vB0 = *(const bf16x8*)&Vs[bB][vb2 + ((hi * 8)      ^ ksw)];
            const bf16x8 vB1 = *(const bf16x8*)&Vs[bB][vb2 + ((hi * 8 + 32) ^ ksw)];
            accO[n] = __builtin_amdgcn_mfma_f32_16x16x32_bf16(p0.v, vA0, accO[n], 0, 0, 0);
            accO[n] = __builtin_amdgcn_mfma_f32_16x16x32_bf16(p1.v, vA1, accO[n], 0, 0, 0);
            accO[n] = __builtin_amdgcn_mfma_f32_16x16x32_bf16(p2.v, vB0, accO[n], 0, 0, 0);
            accO[n] = __builtin_amdgcn_mfma_f32_16x16x32_bf16(p3.v, vB1, accO[n], 0, 0, 0);
        }
        __builtin_amdgcn_s_setprio(0);
    }

    // final lsum reduction across the 4 row-lanes
    float ts = lsum;
    ts += __shfl_xor(ts, 16);
    ts += __shfl_xor(ts, 32);
    float linv[4];
#pragma unroll
    for (int r = 0; r < 4; ++r) linv[r] = 1.f / __shfl(ts, hi * 4 + r);
#pragma unroll
    for (int n = 0; n < 4; ++n)
#pragma unroll
        for (int r = 0; r < 4; ++r)
            O[((size_t)(b * kS + q0 + w * 16 + hi * 4 + r)) * kD
              + h * 64 + n * 16 + lo] = f2bf(accO[n][r] * linv[r]);
}

// ---------------------------------------------------------------------------
// out = LayerNorm(a + r), all bf16; wave-per-row, ushort4 loads
// ---------------------------------------------------------------------------
__global__ __launch_bounds__(256) void add_ln_bf(
    const u16* __restrict__ a, const u16* __restrict__ r,
    const float* __restrict__ g, const float* __restrict__ bt,
    u16* __restrict__ out)
{
    const int lane = threadIdx.x & 63;
    const size_t row = (size_t)blockIdx.x * 4 + (threadIdx.x >> 6);
    const ushort4* a4 = (const ushort4*)(a + row * kD);
    const ushort4* r4 = (const ushort4*)(r + row * kD);
    float v[3][4];
    float s = 0.f;
#pragma unroll
    for (int j = 0; j < 3; ++j) {
        const ushort4 av = a4[j * 64 + lane];
        const ushort4 rv = r4[j * 64 + lane];
        v[j][0] = b2f(av.x) + b2f(rv.x);
        v[j][1] = b2f(av.y) + b2f(rv.y);
        v[j][2] = b2f(av.z) + b2f(rv.z);
        v[j][3] = b2f(av.w) + b2f(rv.w);
        s += v[j][0] + v[j][1] + v[j][2] + v[j][3];
    }
#pragma unroll
    for (int off = 32; off; off >>= 1) s += __shfl_xor(s, off);
    const float mu = s * (1.f / 768.f);
    float vs = 0.f;
#pragma unroll
    for (int j = 0; j < 3; ++j)
#pragma unroll
        for (int e = 0; e < 4; ++e) {
            const float t0 = v[j][e] - mu;
            vs = fmaf(t0, t0, vs);
        }
#pragma unroll
    for (int off = 32; off; off >>= 1) vs += __shfl_xor(vs, off);
    const float rstd = rsqrtf(vs * (1.f / 768.f) + 1e-5f);
    const float4* g4 = (const float4*)g;
    const float4* b4 = (const float4*)bt;
#pragma unroll
    for (int j = 0; j < 3; ++j) {
        const float4 gv = g4[j * 64 + lane];
        const float4 bv = b4[j * 64 + lane];
        ushort4 o;
        o.x = f2bf((v[j][0] - mu) * rstd * gv.x + bv.x);
        o.y = f2bf((v[j][1] - mu) * rstd * gv.y + bv.y);
        o.z = f2bf((v[j][2] - mu) * rstd * gv.z + bv.z);
        o.w = f2bf((v[j][3] - mu) * rstd * gv.w + bv.w);
        ((ushort4*)(out + row * kD))[j * 64 + lane] = o;
    }
}

// ---------------------------------------------------------------------------
// mean over s (bf16 input): 2-stage deterministic reduction
// ---------------------------------------------------------------------------
__global__ __launch_bounds__(192) void mean_part_bf(
    const u16* __restrict__ x, float* __restrict__ mred)
{
    const int c = blockIdx.x, b = blockIdx.y;
    const int d = threadIdx.x * 4;
    const u16* base = x + ((size_t)b * kS + c * 32) * kD + d;
    float s0 = 0.f, s1 = 0.f, s2 = 0.f, s3 = 0.f;
#pragma unroll 8
    for (int t = 0; t < 32; ++t) {
        const ushort4 u = *(const ushort4*)(base + (size_t)t * kD);
        s0 += b2f(u.x); s1 += b2f(u.y); s2 += b2f(u.z); s3 += b2f(u.w);
    }
    float4 o; o.x = s0; o.y = s1; o.z = s2; o.w = s3;
    *(float4*)(mred + ((size_t)b * 64 + c) * kD + d) = o;
}

__global__ __launch_bounds__(256) void mean_fin(
    const float* __restrict__ mred, float* __restrict__ out)
{
    const int d = blockIdx.x * 256 + threadIdx.x;
    const int b = blockIdx.y;
    float s = 0.f;
#pragma unroll
    for (int c = 0; c < 64; ++c) s += mred[((size_t)b * 64 + c) * kD + d];
    out[b * kD + d] = s * (1.f / 2048.f);
}

// ---------------------------------------------------------------------------
// FALLBACK f32 kernels (used only if ws too small)
// ---------------------------------------------------------------------------
__global__ __launch_bounds__(256) void add_ln_f32(
    const float* __restrict__ a, const float* __restrict__ r,
    const float* __restrict__ g, const float* __restrict__ bt,
    float* __restrict__ out)
{
    const int lane = threadIdx.x & 63;
    const size_t row = (size_t)blockIdx.x * 4 + (threadIdx.x >> 6);
    const float4* a4 = (const float4*)(a + row * kD);
    const float4* r4 = (const float4*)(r + row * kD);
    float4 v[3];
    float s = 0.f;
#pragma unroll
    for (int j = 0; j < 3; ++j) {
        const float4 av = a4[j * 64 + lane];
        const float4 rv = r4[j * 64 + lane];
        v[j].x = av.x + rv.x; v[j].y = av.y + rv.y;
        v[j].z = av.z + rv.z; v[j].w = av.w + rv.w;
        s += v[j].x + v[j].y + v[j].z + v[j].w;
    }
#pragma unroll
    for (int off = 32; off; off >>= 1) s += __shfl_xor(s, off);
    const float mu = s * (1.f / 768.f);
    float vs = 0.f;
#pragma unroll
    for (int j = 0; j < 3; ++j) {
        float t0 = v[j].x - mu, t1 = v[j].y - mu, t2 = v[j].z - mu, t3 = v[j].w - mu;
        vs = fmaf(t0, t0, fmaf(t1, t1, fmaf(t2, t2, fmaf(t3, t3, vs))));
    }
#pragma unroll
    for (int off = 32; off; off >>= 1) vs += __shfl_xor(vs, off);
    const float rstd = rsqrtf(vs * (1.f / 768.f) + 1e-5f);
    const float4* g4 = (const float4*)g;
    const float4* b4 = (const float4*)bt;
#pragma unroll
    for (int j = 0; j < 3; ++j) {
        const float4 gv = g4[j * 64 + lane];
        const float4 bv = b4[j * 64 + lane];
        float4 o;
        o.x = (v[j].x - mu) * rstd * gv.x + bv.x;
        o.y = (v[j].y - mu) * rstd * gv.y + bv.y;
        o.z = (v[j].z - mu) * rstd * gv.z + bv.z;
        o.w = (v[j].w - mu) * rstd * gv.w + bv.w;
        ((float4*)(out + row * kD))[j * 64 + lane] = o;
    }
}

__global__ __launch_bounds__(256) void mean_s(
    const float* __restrict__ x, float* __restrict__ out)
{
    const int d = blockIdx.x * 256 + threadIdx.x;
    const int b = blockIdx.y;
    float s = 0.f;
    for (int t = 0; t < kS; ++t) s += x[((size_t)b * kS + t) * kD + d];
    out[b * kD + d] = s * (1.f / 2048.f);
}

__global__ __launch_bounds__(256) void gemm_f32(
    const float* __restrict__ A, const float* __restrict__ W,
    const float* __restrict__ bias, float* __restrict__ C,
    int M, int N, int K, int relu)
{
    __shared__ float As[16][68];
    __shared__ float Bs[16][68];
    const int tid = threadIdx.x;
    const int row0 = blockIdx.x << 6;
    const int col0 = blockIdx.y << 6;
    const int tx = tid & 15, ty = tid >> 4;
    const int ar = tid >> 2;
    const int ak = (tid & 3) << 2;
    const int bk = tid >> 4;
    const int bc = (tid & 15) << 2;
    float acc[4][4] = {};
    const float* Ap = A + (size_t)(row0 + ar) * K + ak;
    const float* Wp = W + (size_t)bk * N + col0 + bc;
    for (int k0 = 0; k0 < K; k0 += 16) {
        const float4 a4 = *(const float4*)(Ap + k0);
        const float4 b4 = *(const float4*)(Wp + (size_t)k0 * N);
        __syncthreads();
        As[ak + 0][ar] = a4.x; As[ak + 1][ar] = a4.y;
        As[ak + 2][ar] = a4.z; As[ak + 3][ar] = a4.w;
        *(float4*)&Bs[bk][bc] = b4;
        __syncthreads();
#pragma unroll
        for (int kk = 0; kk < 16; ++kk) {
            const float4 av = *(const float4*)&As[kk][ty << 2];
            const float4 bv = *(const float4*)&Bs[kk][tx << 2];
            const float aa[4] = {av.x, av.y, av.z, av.w};
            const float bb[4] = {bv.x, bv.y, bv.z, bv.w};
#pragma unroll
            for (int i = 0; i < 4; ++i)
#pragma unroll
                for (int j = 0; j < 4; ++j)
                    acc[i][j] = fmaf(aa[i], bb[j], acc[i][j]);
        }
    }
#pragma unroll
    for (int i = 0; i < 4; ++i) {
        const int row = row0 + (ty << 2) + i;
#pragma unroll
        for (int j = 0; j < 4; ++j) {
            const int col = col0 + (tx << 2) + j;
            float v = acc[i][j] + bias[col];
            if (relu) v = fmaxf(v, 0.f);
            C[(size_t)row * N + col] = v;
        }
    }
}

__global__ __launch_bounds__(256) void attn_fused(
    const float* __restrict__ Q, const float* __restrict__ Km,
    const float* __restrict__ Vm, const int* __restrict__ ids,
    float* __restrict__ O)
{
    __shared__ float Ksf[64 * 64];
    __shared__ float Vtf[64 * 64];
    __shared__ float Qs[16][64];
    __shared__ float Psf[4][4][64];
    const int tid = threadIdx.x;
    const int w = tid >> 6;
    const int lane = tid & 63;
    const int h = blockIdx.y, b = blockIdx.z;
    const int qrow0 = blockIdx.x << 4;
    {
        const int r = tid >> 4;
        const int c4 = tid & 15;
        const float4 q4 = *(const float4*)(
            Q + ((size_t)(b * kS + qrow0 + r)) * kD + h * 64 + (c4 << 2));
        Qs[r][(c4 << 2) + 0] = q4.x * 0.125f;
        Qs[r][(c4 << 2) + 1] = q4.y * 0.125f;
        Qs[r][(c4 << 2) + 2] = q4.z * 0.125f;
        Qs[r][(c4 << 2) + 3] = q4.w * 0.125f;
    }
    float m[4], lsum[4], o[4];
#pragma unroll
    for (int r = 0; r < 4; ++r) { m[r] = -3.0e38f; lsum[r] = 0.f; o[r] = 0.f; }
    for (int kt = 0; kt < kS / 64; ++kt) {
        __syncthreads();
#pragma unroll
        for (int i = 0; i < 4; ++i) {
            const int lin = tid + (i << 8);
            const int row = lin >> 4;
            const int s4 = lin & 15;
            const size_t gro = ((size_t)(b * kS + (kt << 6) + row)) * kD + h * 64 + (s4 << 2);
            const float4 k4 = *(const float4*)(Km + gro);
            ((float4*)Ksf)[(row << 4) + (s4 ^ (row & 7))] = k4;
            const float4 v4 = *(const float4*)(Vm + gro);
            const int ksl = row >> 2, ke = row & 3;
            const int d0 = s4 << 2;
            Vtf[(d0 + 0) * 64 + ((ksl ^ ((d0 + 0) & 7)) << 2) + ke] = v4.x;
            Vtf[(d0 + 1) * 64 + ((ksl ^ ((d0 + 1) & 7)) << 2) + ke] = v4.y;
            Vtf[(d0 + 2) * 64 + ((ksl ^ ((d0 + 2) & 7)) << 2) + ke] = v4.z;
            Vtf[(d0 + 3) * 64 + ((ksl ^ ((d0 + 3) & 7)) << 2) + ke] = v4.w;
        }
        __syncthreads();
        const bool masked = (ids[(size_t)b * kS + (kt << 6) + lane] == 1);
        float scr[4] = {0.f, 0.f, 0.f, 0.f};
#pragma unroll
        for (int i16 = 0; i16 < 16; ++i16) {
            const float4 kv = ((const float4*)Ksf)[(lane << 4) + (i16 ^ (lane & 7))];
#pragma unroll
            for (int r = 0; r < 4; ++r) {
                const float4 qv = *(const float4*)&Qs[(w << 2) + r][i16 << 2];
                scr[r] = fmaf(kv.x, qv.x, fmaf(kv.y, qv.y,
                          fmaf(kv.z, qv.z, fmaf(kv.w, qv.w, scr[r]))));
            }
        }
#pragma unroll
        for (int r = 0; r < 4; ++r) {
            float sm = masked ? -3.0e38f : scr[r];
#pragma unroll
            for (int off = 32; off; off >>= 1) sm = fmaxf(sm, __shfl_xor(sm, off));
            const float mn = fmaxf(m[r], sm);
            const float cr = __expf(m[r] - mn);
            const float pv = masked ? 0.f : __expf(scr[r] - mn);
            float ps = pv;
#pragma unroll
            for (int off = 32; off; off >>= 1) ps += __shfl_xor(ps, off);
            lsum[r] = lsum[r] * cr + ps;
            o[r] *= cr;
            m[r] = mn;
            Psf[w][r][lane] = pv;
        }
#pragma unroll
        for (int i16 = 0; i16 < 16; ++i16) {
            const float4 vv = ((const float4*)Vtf)[(lane << 4) + (i16 ^ (lane & 7))];
#pragma unroll
            for (int r = 0; r < 4; ++r) {
                const float4 pv = *(const float4*)&Psf[w][r][i16 << 2];
                o[r] = fmaf(pv.x, vv.x, fmaf(pv.y, vv.y,
                        fmaf(pv.z, vv.z, fmaf(pv.w, vv.w, o[r]))));
            }
        }
    }
#pragma unroll
    for (int r = 0; r < 4; ++r)
        O[((size_t)(b * kS + qrow0 + (w << 2) + r)) * kD + h * 64 + lane] =
            o[r] / lsum[r];
}

// ---------------------------------------------------------------------------
// Host orchestration
// ---------------------------------------------------------------------------
extern "C" void kernel_launch(void* const* d_in, const int* in_sizes, int n_in,
                              void* d_out, int out_size, void* d_ws, size_t ws_size,
                              hipStream_t stream)
{
    const int*   ids   = (const int*)  d_in[0];
    const float* emb   = (const float*)d_in[1];
    const float* Wq    = (const float*)d_in[2];
    const float* bq    = (const float*)d_in[3];
    const float* Wk    = (const float*)d_in[4];
    const float* bk    = (const float*)d_in[5];
    const float* Wv    = (const float*)d_in[6];
    const float* bv    = (const float*)d_in[7];
    const float* Wo    = (const float*)d_in[8];
    const float* bo    = (const float*)d_in[9];
    const float* W1    = (const float*)d_in[10];
    const float* b1    = (const float*)d_in[11];
    const float* W2    = (const float*)d_in[12];
    const float* b2    = (const float*)d_in[13];
    const float* gamma = (const float*)d_in[14];
    const float* beta  = (const float*)d_in[15];
    float* out = (float*)d_out;

    const size_t BUFE = (size_t)kB * kS * kD;          // 6,291,456
    const size_t WDD  = (size_t)kD * kD;
    const size_t WDF  = (size_t)kD * kF;
    const size_t HIDE = (size_t)kB * kS * kF;          // hidden/qkv scratch elems
    const int NTOK = kB * kS;                          // 8192

    const size_t NEED = BUFE * 2 * 4                   // xb, x1b, ao, ob (bf16)
                      + HIDE * 2                       // shared qkv/hidden scratch
                      + WARENA_E * 2                   // weight arena
                      + (size_t)6 * 6912 * 4           // bias arena
                      + 128 * 8                        // mask bits
                      + (size_t)kB * 64 * kD * 4;      // mean partials

    if (ws_size >= NEED) {
        u16*   xb  = (u16*)d_ws;                       // residual stream (bf16)
        u16*   x1b = xb + BUFE;
        u16*   ao  = x1b + BUFE;                       // attn out
        u16*   ob  = ao + BUFE;                        // proj/ffn out
        u16*   sc  = ob + BUFE;                        // qkv AND ffn-hidden
        u16*   vtb = sc + (size_t)NTOK * kQW;          // vT aliases sc tail
        u16*   wa  = sc + HIDE;
        float* ba  = (float*)(wa + WARENA_E);
        u64*   mbt = (u64*)(ba + 6 * 6912);
        float* mrd = (float*)(mbt + 128);

        embed_pe<<<NTOK, 256, 0, stream>>>(ids, emb, xb);
        mk_maskbits<<<kB * kS / 64, 64, 0, stream>>>(ids, mbt);
        bias_build<<<(6 * 6912 + 255) / 256, 256, 0, stream>>>(
            bq, bk, bv, bo, b1, b2, ba);

        for (int l = 0; l < kL; ++l) {
            const size_t oDD = (size_t)l * WDD;
            const size_t oDF = (size_t)l * WDF;
            const float* bl = ba + (size_t)l * 6912;
            const float* gl  = gamma + (size_t)l * kD;
            const float* btl = beta  + (size_t)l * kD;

            cvt_all<<<1728, 256, 0, stream>>>(
                Wq + oDD, Wk + oDD, Wv + oDD, Wo + oDD, W1 + oDF, W2 + oDF, wa);

            // fused QKV (Q pre-scaled); V -> permuted vT
            gemm256b<<<dim3(64, 9), 256, 0, stream>>>(
                xb, wa, bl, sc, vtb, NTOK, kQW, kD, 3);

            attn_mfma<<<dim3(kS / 128, kH, kB), 512, 0, stream>>>(
                sc, vtb, mbt, ao);

            gemm_bf16<<<dim3(64, 6), 256, 0, stream>>>(
                ao, wa + OFF_WO, bl + 2304, ob, nullptr, NTOK, kD, kD, 1);

            // x1 = LN(x + o)
            add_ln_bf<<<NTOK / 4, 256, 0, stream>>>(xb, ob, gl, btl, x1b);

            // FFN: hidden -> sc, down-proj
            gemm256b<<<dim3(64, 12), 256, 0, stream>>>(
                x1b, wa + OFF_W1, bl + 3072, sc, nullptr, NTOK, kF, kD, 2);
            gemm_bf16<<<dim3(64, 6), 256, 0, stream>>>(
                sc, wa + OFF_W2, bl + 6144, ob, nullptr, NTOK, kD, kF, 1);

            // x = LN(x1 + ffn)
            add_ln_bf<<<NTOK / 4, 256, 0, stream>>>(x1b, ob, gl, btl, xb);
        }

        mean_part_bf<<<dim3(64, kB), 192, 0, stream>>>(xb, mrd);
        mean_fin<<<dim3(kD / 256, kB), 256, 0, stream>>>(mrd, out);
        return;
    }

    // -------- fallback f32 path --------
    if (ws_size < 5 * BUFE * sizeof(float)) return;
    float* xb = (float*)d_ws;
    float* kb = xb + BUFE;
    float* qb = kb + BUFE;
    float* vb = qb + BUFE;
    float* obf = vb + BUFE;
    float* hb = qb;

    embed_pe_f32<<<NTOK, 256, 0, stream>>>(ids, emb, xb);
    for (int l = 0; l < kL; ++l) {
        const size_t oDD = (size_t)l * WDD;
        const size_t oDF = (size_t)l * WDF;
        gemm_f32<<<dim3(NTOK / 64, kD / 64), 256, 0, stream>>>(
            xb, Wq + oDD, bq + (size_t)l * kD, qb, NTOK, kD, kD, 0);
        gemm_f32<<<dim3(NTOK / 64, kD / 64), 256, 0, stream>>>(
            xb, Wk + oDD, bk + (size_t)l * kD, kb, NTOK, kD, kD, 0);
        gemm_f32<<<dim3(NTOK / 64, kD / 64), 256, 0, stream>>>(
            xb, Wv + oDD, bv + (size_t)l * kD, vb, NTOK, kD, kD, 0);
        attn_fused<<<dim3(kS / 16, kH, kB), 256, 0, stream>>>(qb, kb, vb, ids, obf);
        gemm_f32<<<dim3(NTOK / 64, kD / 64), 256, 0, stream>>>(
            obf, Wo + oDD, bo + (size_t)l * kD, qb, NTOK, kD, kD, 0);
        add_ln_f32<<<NTOK / 4, 256, 0, stream>>>(xb, qb,
            gamma + (size_t)l * kD, beta + (size_t)l * kD, kb);
        for (int c = 0; c < 2; ++c) {
            const size_t ro = (size_t)c * 4096;
            gemm_f32<<<dim3(4096 / 64, kF / 64), 256, 0, stream>>>(
                kb + ro * kD, W1 + oDF, b1 + (size_t)l * kF, hb, 4096, kF, kD, 1);
            gemm_f32<<<dim3(4096 / 64, kD / 64), 256, 0, stream>>>(
                hb, W2 + oDF, b2 + (size_t)l * kD, obf + ro * kD, 4096, kD, kF, 0);
        }
        add_ln_f32<<<NTOK / 4, 256, 0, stream>>>(kb, obf,
            gamma + (size_t)l * kD, beta + (size_t)l * kD, xb);
    }
    mean_s<<<dim3(kD / 256, kB), 256, 0, stream>>>(xb, out);
}